// Round 5
// baseline (272.563 us; speedup 1.0000x reference)
//
#include <hip/hip_runtime.h>
#include <cstdint>
#include <cstddef>

#define NB 4
#define NP 4096
#define OD 128
#define LOG2E 1.44269504f

typedef _Float16 h16;
typedef _Float16 h16x8 __attribute__((ext_vector_type(8)));
typedef _Float16 h16x4 __attribute__((ext_vector_type(4)));
typedef _Float16 h16x2 __attribute__((ext_vector_type(2)));
typedef float    f32x4 __attribute__((ext_vector_type(4)));

__device__ __forceinline__ void async16(const void* g, void* l) {
    __builtin_amdgcn_global_load_lds(
        (const __attribute__((address_space(1))) void*)g,
        (__attribute__((address_space(3))) void*)l, 16, 0, 0);
}

__device__ __forceinline__ h16x8 pack8(f32x4 a, f32x4 b) {
    h16x2 p0 = __builtin_bit_cast(h16x2, __builtin_amdgcn_cvt_pkrtz(a[0], a[1]));
    h16x2 p1 = __builtin_bit_cast(h16x2, __builtin_amdgcn_cvt_pkrtz(a[2], a[3]));
    h16x2 p2 = __builtin_bit_cast(h16x2, __builtin_amdgcn_cvt_pkrtz(b[0], b[1]));
    h16x2 p3 = __builtin_bit_cast(h16x2, __builtin_amdgcn_cvt_pkrtz(b[2], b[3]));
    return (h16x8){p0[0], p0[1], p1[0], p1[1], p2[0], p2[1], p3[0], p3[1]};
}

// ---------------------------------------------------------------------------
// W fp32 -> fp16 pre-swizzled image: per (mat,kc): 512 slots of 16B,
// slot = o*4 + csw, content = k-chunk (csw ^ ((o>>1)&3)).
// ---------------------------------------------------------------------------
__global__ __launch_bounds__(256) void wcvt(
    const float* __restrict__ Wq, const float* __restrict__ Wk,
    const float* __restrict__ Wv, h16* __restrict__ W16s)
{
    int g = blockIdx.x * 256 + threadIdx.x;        // 49152 slots
    int mat = g >> 14, r = g & 16383;
    int kc = r >> 9, q = r & 511, o = q >> 2, csw = q & 3;
    int c = csw ^ ((o >> 1) & 3);
    const float* W = (mat == 0) ? Wq : (mat == 1) ? Wk : Wv;
    const float* src = W + (size_t)o * 1024 + kc * 32 + 8 * c;
    f32x4 a = *(const f32x4*)src;
    f32x4 b = *(const f32x4*)(src + 4);
    h16x8 h = {(h16)a.x, (h16)a.y, (h16)a.z, (h16)a.w,
               (h16)b.x, (h16)b.y, (h16)b.z, (h16)b.w};
    *(h16x8*)&W16s[(size_t)g * 8] = h;
}

// ---------------------------------------------------------------------------
// Fused Q/K/V conv-GEMM, tile 128o x 64n. x staged once, reused by 3 mats.
// W double-buffered via global_load_lds; x 2-deep register prefetch.
// LDS 59.5 KB -> 2 blocks/CU. Q scaled by log2(e) for exp2 softmax.
// qt/kt [b][n][o]; vt [b][o][n] (plain).
// ---------------------------------------------------------------------------
__global__ __launch_bounds__(256, 2) void conv_qkv(
    const float* __restrict__ x, const h16* __restrict__ W16s,
    const float* __restrict__ bq, const float* __restrict__ bk,
    const float* __restrict__ bv,
    h16* __restrict__ qt, h16* __restrict__ kt, h16* __restrict__ vt)
{
    const int nt = blockIdx.x;            // 64 tiles of 64 n
    const int b  = blockIdx.y;
    const int tid = threadIdx.x, lane = tid & 63, wv = tid >> 6;
    const int lr = lane & 15, qd = lane >> 4;
    const int o_w = 32 * wv;

    __shared__ __align__(16) char smem[60928];
    // Wbuf[2] @ 0/24576 (3 mats * 8192 each); xb[2] @ 49152/54272 (5120); bias @ 59392
    float* biasl = (float*)(smem + 59392);
    if (tid < 128) {
        biasl[tid] = bq[tid]; biasl[128 + tid] = bk[tid]; biasl[256 + tid] = bv[tid];
    }

    auto dmaW = [&](int kc, int bs) {
#pragma unroll
        for (int t = 0; t < 6; ++t) {
            int grp = wv * 6 + t;               // 24 groups of 64 slots
            int mat = grp >> 3, sg = grp & 7;
            async16(W16s + ((size_t)(mat * 32 + kc) * 512 + sg * 64 + lane) * 8,
                    smem + bs * 24576 + mat * 8192 + sg * 1024);
        }
    };

    f32x4 xr[2][2];
    auto xload = [&](int kc, int sl) {
        int n = tid >> 2, kg = tid & 3;
        int c = kg >> 1, kh2 = (kg & 1) * 2;
        const float* p = &x[(((size_t)(b * 64 + 2 * kc + c) * 256) + 4 * nt + kh2) * 256 + 4 * n];
        xr[sl][0] = *(const f32x4*)p;
        xr[sl][1] = *(const f32x4*)(p + 256);
    };
    auto xwrite = [&](int sl, int xbs) {
        int n = tid >> 2, kg = tid & 3;
        int c = kg >> 1, kh2 = (kg & 1) * 2;
        h16x8 h = {(h16)xr[sl][0].x, (h16)xr[sl][0].y, (h16)xr[sl][0].z, (h16)xr[sl][0].w,
                   (h16)xr[sl][1].x, (h16)xr[sl][1].y, (h16)xr[sl][1].z, (h16)xr[sl][1].w};
        *(h16x8*)(smem + 49152 + xbs * 5120 + n * 80 + c * 32 + kh2 * 8) = h;
    };

    f32x4 acc[3][2][4];
#pragma unroll
    for (int m = 0; m < 3; ++m)
#pragma unroll
        for (int a = 0; a < 2; ++a)
#pragma unroll
            for (int c = 0; c < 4; ++c) acc[m][a][c] = (f32x4){0.f, 0.f, 0.f, 0.f};

    xload(0, 0); dmaW(0, 0);
    xload(1, 1);
    xwrite(0, 0);
    __syncthreads();

    for (int kc = 0; kc < 32; ++kc) {
        int c = kc & 1;
        if (kc + 1 < 32) dmaW(kc + 1, 1 - c);
        if (kc + 2 < 32) xload(kc + 2, c);

        const h16* Xl = (const h16*)(smem + 49152 + c * 5120);
        const char* Wl = smem + c * 24576;

        h16x8 bf[4];
#pragma unroll
        for (int tn = 0; tn < 4; ++tn)
            bf[tn] = *(const h16x8*)&Xl[(16 * tn + lr) * 40 + 8 * qd];
#pragma unroll
        for (int mat = 0; mat < 3; ++mat) {
            h16x8 af[2];
#pragma unroll
            for (int to = 0; to < 2; ++to) {
                int o = o_w + 16 * to + lr;
                af[to] = *(const h16x8*)(Wl + mat * 8192 + (size_t)(o * 4 + (qd ^ ((o >> 1) & 3))) * 16);
            }
#pragma unroll
            for (int to = 0; to < 2; ++to)
#pragma unroll
                for (int tn = 0; tn < 4; ++tn)
                    acc[mat][to][tn] = __builtin_amdgcn_mfma_f32_16x16x32_f16(af[to], bf[tn], acc[mat][to][tn], 0, 0, 0);
        }
        if (kc + 1 < 32) xwrite((kc + 1) & 1, 1 - c);
        __syncthreads();
    }

    const int n0 = nt * 64;
    // Q (scaled by log2e), K: [b][n][o] via bounce [64 n][136 o]
#pragma unroll
    for (int mat = 0; mat < 2; ++mat) {
        h16* bnc = (h16*)smem;
        const float qs = (mat == 0) ? LOG2E : 1.0f;
#pragma unroll
        for (int to = 0; to < 2; ++to)
#pragma unroll
            for (int tn = 0; tn < 4; ++tn) {
                int ob = o_w + 16 * to + 4 * qd;
                int n  = 16 * tn + lr;
                h16x4 hv = {(h16)((acc[mat][to][tn][0] + biasl[mat * 128 + ob]) * qs),
                            (h16)((acc[mat][to][tn][1] + biasl[mat * 128 + ob + 1]) * qs),
                            (h16)((acc[mat][to][tn][2] + biasl[mat * 128 + ob + 2]) * qs),
                            (h16)((acc[mat][to][tn][3] + biasl[mat * 128 + ob + 3]) * qs)};
                *(h16x4*)&bnc[n * 136 + ob] = hv;
            }
        __syncthreads();
        h16* dst = mat ? kt : qt;
#pragma unroll
        for (int j = 0; j < 4; ++j) {
            int s = tid + 256 * j;
            int n = s >> 4, oc = s & 15;
            *(h16x8*)(dst + ((size_t)(b * NP + n0 + n)) * OD + 8 * oc) = *(h16x8*)&bnc[n * 136 + 8 * oc];
        }
        __syncthreads();
    }
    // V: [b][o][n] via bounce [128 o][72 n]
    {
        h16* bnc = (h16*)smem;
#pragma unroll
        for (int to = 0; to < 2; ++to)
#pragma unroll
            for (int tn = 0; tn < 4; ++tn)
#pragma unroll
                for (int r = 0; r < 4; ++r) {
                    int o = o_w + 16 * to + 4 * qd + r;
                    int n = 16 * tn + lr;
                    bnc[o * 72 + n] = (h16)(acc[2][to][tn][r] + biasl[256 + o]);
                }
        __syncthreads();
#pragma unroll
        for (int j = 0; j < 4; ++j) {
            int s = tid + 256 * j;
            int o = s >> 3, ch = s & 7;
            *(h16x8*)(vt + ((size_t)(b * OD + o)) * NP + n0 + 8 * ch) = *(h16x8*)&bnc[o * 72 + 8 * ch];
        }
    }
}

// ---------------------------------------------------------------------------
// Flash attention, split-K. 4 waves x 32 Q-rows. S^T = mfma(K,Q) with
// K-rows PERMUTED in LDS (row l <- m = 8*((l>>2)&3) + 4*(l>>4) + (l&3)) so
// P exits in 16x16x32 B-operand layout (k==m) -> PV at K=32, V fragments are
// natural contiguous h16x8. exp2 softmax (Q pre-scaled). One barrier/iter.
// ---------------------------------------------------------------------------
template <int SP>
__global__ __launch_bounds__(256, 4) void flash_attn(
    const h16* __restrict__ qt, const h16* __restrict__ kt,
    const h16* __restrict__ vt, h16* __restrict__ po, float2* __restrict__ ml)
{
    constexpr int MR  = NP / SP;
    constexpr int NIT = MR / 32;
    const int nt = blockIdx.x, sp = blockIdx.y, b = blockIdx.z;
    const int tid = threadIdx.x, lane = tid & 63, wv = tid >> 6;
    const int lr = lane & 15, qd = lane >> 4;

    __shared__ __align__(16) char smem[32768];   // K[2]@0/8192, V[2]@16384/24576

    // Q fragments (B-operand): col n = lr, k = 32kc + 8qd + j
    h16x8 qf[2][4];
#pragma unroll
    for (int rt = 0; rt < 2; ++rt)
#pragma unroll
        for (int kc = 0; kc < 4; ++kc)
            qf[rt][kc] = *(const h16x8*)&qt[((size_t)(b * NP + nt * 128 + 32 * wv + 16 * rt + lr)) * OD
                                            + 32 * kc + 8 * qd];

    float m_run[2] = {-1e30f, -1e30f}, l_run[2] = {0.f, 0.f};
    f32x4 oacc[2][8];
#pragma unroll
    for (int rt = 0; rt < 2; ++rt)
#pragma unroll
        for (int t = 0; t < 8; ++t) oacc[rt][t] = (f32x4){0.f, 0.f, 0.f, 0.f};

    auto dma = [&](int it, int bs) {
        int m0 = sp * MR + it * 32;
#pragma unroll
        for (int t = 0; t < 2; ++t) {            // K: permuted rows, swizzled chunks
            int s = wv * 128 + t * 64 + lane;
            int l = s >> 4, cst = s & 15, csrc = cst ^ (l & 15);
            int m = m0 + 8 * ((l >> 2) & 3) + 4 * (l >> 4) + (l & 3);
            async16(kt + ((size_t)(b * NP + m)) * OD + 8 * csrc,
                    smem + bs * 8192 + (wv * 128 + t * 64) * 16);
        }
#pragma unroll
        for (int t = 0; t < 2; ++t) {            // V: rows o, chunks swizzled
            int s = wv * 128 + t * 64 + lane;
            int o = s >> 2, cst = s & 3, csrc = cst ^ ((o & 3) ^ ((o >> 2) & 3));
            async16(vt + ((size_t)(b * OD + o)) * NP + m0 + 8 * csrc,
                    smem + 16384 + bs * 8192 + (wv * 128 + t * 64) * 16);
        }
    };

    dma(0, 0);
    __syncthreads();

    for (int it = 0; it < NIT; ++it) {
        int c = it & 1;
        if (it + 1 < NIT) dma(it + 1, 1 - c);
        const h16* Kb = (const h16*)(smem + c * 8192);
        const h16* Vb = (const h16*)(smem + 16384 + c * 8192);

        // S^T: per lane col n = lr; regs (mt, r) hold m = 8qd + 4mt + r
        f32x4 sc[2][2];
#pragma unroll
        for (int rt = 0; rt < 2; ++rt)
#pragma unroll
            for (int mt = 0; mt < 2; ++mt) sc[rt][mt] = (f32x4){0.f, 0.f, 0.f, 0.f};
#pragma unroll
        for (int mt = 0; mt < 2; ++mt)
#pragma unroll
            for (int kc = 0; kc < 4; ++kc) {
                h16x8 kf = *(const h16x8*)&Kb[(size_t)((16 * mt + lr) * 16 + ((4 * kc + qd) ^ lr)) * 8];
                sc[0][mt] = __builtin_amdgcn_mfma_f32_16x16x32_f16(kf, qf[0][kc], sc[0][mt], 0, 0, 0);
                sc[1][mt] = __builtin_amdgcn_mfma_f32_16x16x32_f16(kf, qf[1][kc], sc[1][mt], 0, 0, 0);
            }

        // online softmax in exp2 domain (scores pre-scaled by log2e via Q)
        h16x8 pf[2];
        float al[2];
#pragma unroll
        for (int rt = 0; rt < 2; ++rt) {
            float mx = fmaxf(fmaxf(fmaxf(sc[rt][0][0], sc[rt][0][1]), fmaxf(sc[rt][0][2], sc[rt][0][3])),
                             fmaxf(fmaxf(sc[rt][1][0], sc[rt][1][1]), fmaxf(sc[rt][1][2], sc[rt][1][3])));
            mx = fmaxf(mx, __shfl_xor(mx, 16));
            mx = fmaxf(mx, __shfl_xor(mx, 32));
            float mn = fmaxf(m_run[rt], mx);
            al[rt] = __builtin_amdgcn_exp2f(m_run[rt] - mn);
            m_run[rt] = mn;
            float rs = 0.f;
#pragma unroll
            for (int mt = 0; mt < 2; ++mt)
#pragma unroll
                for (int r = 0; r < 4; ++r) {
                    float e = __builtin_amdgcn_exp2f(sc[rt][mt][r] - mn);
                    sc[rt][mt][r] = e;
                    rs += e;
                }
            rs += __shfl_xor(rs, 16);
            rs += __shfl_xor(rs, 32);
            l_run[rt] = l_run[rt] * al[rt] + rs;
            pf[rt] = pack8(sc[rt][0], sc[rt][1]);
        }
#pragma unroll
        for (int rt = 0; rt < 2; ++rt)
#pragma unroll
            for (int to = 0; to < 8; ++to)
#pragma unroll
                for (int r = 0; r < 4; ++r) oacc[rt][to][r] *= al[rt];

        // PV at K=32: A = V rows (k = m, natural), B = P (from registers)
#pragma unroll
        for (int to = 0; to < 8; ++to) {
            int o = 16 * to + lr;
            h16x8 va = *(const h16x8*)&Vb[(size_t)(o * 4 + (qd ^ ((o & 3) ^ ((o >> 2) & 3)))) * 8];
            oacc[0][to] = __builtin_amdgcn_mfma_f32_16x16x32_f16(va, pf[0], oacc[0][to], 0, 0, 0);
            oacc[1][to] = __builtin_amdgcn_mfma_f32_16x16x32_f16(va, pf[1], oacc[1][to], 0, 0, 0);
        }
        __syncthreads();   // retire K/V[c] reads; drain DMA for next iter
    }

    // epilogue: normalized fp16 partials + (m,l) in exp2 domain
    const size_t nbase = (size_t)(sp * NB + b) * NP + nt * 128 + 32 * wv;
    if (qd == 0) {
#pragma unroll
        for (int rt = 0; rt < 2; ++rt)
            ml[nbase + 16 * rt + lr] = make_float2(m_run[rt], l_run[rt]);
    }
    float inv[2] = {1.f / l_run[0], 1.f / l_run[1]};
#pragma unroll
    for (int rt = 0; rt < 2; ++rt)
#pragma unroll
        for (int to = 0; to < 8; ++to) {
            h16x4 hv = {(h16)(oacc[rt][to][0] * inv[rt]), (h16)(oacc[rt][to][1] * inv[rt]),
                        (h16)(oacc[rt][to][2] * inv[rt]), (h16)(oacc[rt][to][3] * inv[rt])};
            *(h16x4*)&po[(nbase + 16 * rt + lr) * OD + 16 * to + 4 * qd] = hv;
        }
}

// ---------------------------------------------------------------------------
// Combine SP split partials -> out[b][o][n] fp32. 32-n tiles (512 blocks).
// ---------------------------------------------------------------------------
template <int SP>
__global__ __launch_bounds__(256) void combine(
    const h16* __restrict__ po, const float2* __restrict__ ml,
    float* __restrict__ out)
{
    const int nt = blockIdx.x, b = blockIdx.y;
    const int n0 = nt * 32, tid = threadIdx.x;
    __shared__ float w[SP][32];
    __shared__ float bn[32 * 137];

    if (tid < 32) {
        int n = n0 + tid;
        float m[SP], l[SP], M = -1e30f;
#pragma unroll
        for (int s = 0; s < SP; ++s) {
            float2 v = ml[(size_t)(s * NB + b) * NP + n];
            m[s] = v.x; l[s] = v.y;
            M = fmaxf(M, m[s]);
        }
        float d = 0.f, e[SP];
#pragma unroll
        for (int s = 0; s < SP; ++s) { e[s] = l[s] * __builtin_amdgcn_exp2f(m[s] - M); d += e[s]; }
        float id = 1.f / d;
#pragma unroll
        for (int s = 0; s < SP; ++s) w[s][tid] = e[s] * id;
    }
    __syncthreads();

#pragma unroll
    for (int j = 0; j < 2; ++j) {
        int s = tid + 256 * j;
        int n = s >> 4, oc = s & 15;
        float acc[8];
#pragma unroll
        for (int k = 0; k < 8; ++k) acc[k] = 0.f;
#pragma unroll
        for (int sp = 0; sp < SP; ++sp) {
            h16x8 v = *(const h16x8*)&po[((size_t)(sp * NB + b) * NP + n0 + n) * OD + 8 * oc];
            float ww = w[sp][n];
#pragma unroll
            for (int k = 0; k < 8; ++k) acc[k] += ww * (float)v[k];
        }
#pragma unroll
        for (int k = 0; k < 8; ++k) bn[n * 137 + 8 * oc + k] = acc[k];
    }
    __syncthreads();

#pragma unroll
    for (int j = 0; j < 4; ++j) {
        int s = tid + 256 * j;
        int o = s >> 3, ng = s & 7;
        f32x4 r = {bn[(4 * ng + 0) * 137 + o], bn[(4 * ng + 1) * 137 + o],
                   bn[(4 * ng + 2) * 137 + o], bn[(4 * ng + 3) * 137 + o]};
        *(f32x4*)&out[((size_t)(b * OD + o)) * NP + n0 + 4 * ng] = r;
    }
}

extern "C" void kernel_launch(void* const* d_in, const int* in_sizes, int n_in,
                              void* d_out, int out_size, void* d_ws, size_t ws_size,
                              hipStream_t stream) {
    const float* x  = (const float*)d_in[0];
    const float* Wq = (const float*)d_in[1];
    const float* bq = (const float*)d_in[2];
    const float* Wk = (const float*)d_in[3];
    const float* bk = (const float*)d_in[4];
    const float* Wv = (const float*)d_in[5];
    const float* bv = (const float*)d_in[6];

    h16* qtp  = (h16*)d_ws;                                  // 4 MB
    h16* ktp  = qtp + (size_t)NB * NP * OD;                  // 4 MB
    h16* vtp  = ktp + (size_t)NB * NP * OD;                  // 4 MB
    h16* W16s = vtp + (size_t)NB * NP * OD;                  // 768 KB
    h16* po   = W16s + (size_t)3 * 32 * 512 * 8;             // SP*4 MB
    float* out = (float*)d_out;

    wcvt<<<dim3(192), 256, 0, stream>>>(Wq, Wk, Wv, W16s);
    conv_qkv<<<dim3(64, NB), 256, 0, stream>>>(x, W16s, bq, bk, bv, qtp, ktp, vtp);

    const size_t base = 13369344;   // bytes up to po
    const size_t need8 = base + (size_t)8 * NB * NP * OD * 2 + (size_t)8 * NB * NP * 8;
    if (ws_size >= need8) {
        float2* ml = (float2*)(po + (size_t)8 * NB * NP * OD);
        flash_attn<8><<<dim3(32, 8, NB), 256, 0, stream>>>(qtp, ktp, vtp, po, ml);
        combine<8><<<dim3(128, NB), 256, 0, stream>>>(po, ml, out);
    } else {
        float2* ml = (float2*)(po + (size_t)4 * NB * NP * OD);
        flash_attn<4><<<dim3(32, 4, NB), 256, 0, stream>>>(qtp, ktp, vtp, po, ml);
        combine<4><<<dim3(128, NB), 256, 0, stream>>>(po, ml, out);
    }
}